// Round 14
// baseline (29.248 us; speedup 1.0000x reference)
//
#include <hip/hip_runtime.h>
#include <hip/hip_bf16.h>
#include <cstdint>
#include <cstddef>

using short8  = __attribute__((ext_vector_type(8))) short;
using short4v = __attribute__((ext_vector_type(4))) short;
using f32x4   = __attribute__((ext_vector_type(4))) float;

constexpr int NB = 16, NC = 512, ND = 256, NK = 32;
constexpr int ROWS = 16;               // rows per block (1 M-frag per wave)
constexpr int NROW = NB * NC;          // 8192
constexpr int NBLK = NROW / ROWS;      // 512
constexpr int NTHR = 512;              // 8 waves

// 32 KB LDS region, repartitioned over time:
//  phase 1: P f32 [16][512]                      (32768 B)
//  phase 2: Pb bf16 [16][512] swz @0 (16 KB); s_w @16384 (8 KB); s_hb @24576 (8 KB)
//  phase 3: s_ab bf16 [16][256] swz @0 (over dead Pb, 8 KB)
constexpr int OFF_SW = 16384;
constexpr int OFF_HB = 24576;

// d_ws layout (bf16 element offsets) — R6/R9-verified:
//  vW frags [0,65536): fl=nt*8+ks ; oW [65536,131072) ; gW [131072,262144): fl=nt*16+ks
//  h  frags [262144 + b*131072): frag fs=ks*16+nt
constexpr int PVW = 0;
constexpr int POW = 65536;
constexpr int PGW = 131072;
constexpr int PHB = 262144;
constexpr size_t WS_NEED = (size_t)(PHB + NB * 131072) * 2;   // ~4.7 MB

static __device__ __forceinline__ unsigned short f2bf(float f) {
    __hip_bfloat16 b = __float2bfloat16(f);
    return *reinterpret_cast<unsigned short*>(&b);
}
static __device__ __forceinline__ short4v f2bf4(float4 v) {
    short4v r;
    r[0] = (short)f2bf(v.x); r[1] = (short)f2bf(v.y);
    r[2] = (short)f2bf(v.z); r[3] = (short)f2bf(v.w);
    return r;
}

// ---------------------------------------------------------------------------
// merged pack (R6 verbatim): blocks 0..127 weights; 128..1151 h slabs
// ---------------------------------------------------------------------------
__global__ __launch_bounds__(256)
void stk_pack_all(const float* __restrict__ vW, const float* __restrict__ oW,
                  const float* __restrict__ gW, const float* __restrict__ h,
                  unsigned short* __restrict__ ws)
{
    const int blk = blockIdx.x;
    if (blk < 128) {
        const int tid  = blk * 256 + threadIdx.x;      // 32768 threads
        const int lane = tid & 63;
        const int fl   = tid >> 6;                     // 0..511
        const float* src; int nt, ks;
        if (fl < 128)      { src = vW; nt = fl >> 3;         ks = fl & 7;          }
        else if (fl < 256) { src = oW; nt = (fl - 128) >> 3; ks = (fl - 128) & 7;  }
        else               { src = gW; nt = (fl - 256) >> 4; ks = (fl - 256) & 15; }
        const int col = nt * 16 + (lane & 15);
        const int k0  = ks * 32 + (lane >> 4) * 8;
        short8 v;
        #pragma unroll
        for (int j = 0; j < 8; ++j)
            v[j] = (short)f2bf(src[(size_t)(k0 + j) * ND + col]);
        *reinterpret_cast<short8*>(&ws[(size_t)tid * 8]) = v;
    } else {
        const int tid  = (blk - 128) * 256 + threadIdx.x;   // 262144 threads
        const int lane = tid & 63;
        const int fs   = tid >> 6;                     // b*256 + ks*16 + nt
        const int b    = fs >> 8;
        const int ks   = (fs >> 4) & 15;
        const int nt   = fs & 15;
        const float* src = h + (size_t)b * NC * ND;
        const int col = nt * 16 + (lane & 15);
        const int k0  = ks * 32 + (lane >> 4) * 8;
        short8 v;
        #pragma unroll
        for (int j = 0; j < 8; ++j)
            v[j] = (short)f2bf(src[(size_t)(k0 + j) * ND + col]);
        *reinterpret_cast<short8*>(&ws[(size_t)PHB + (size_t)tid * 8]) = v;
    }
}

// ---------------------------------------------------------------------------
// main kernel: 16 rows/block, 512 threads (8 waves), 32 KB LDS -> 4 blocks/CU
// (full 32-wave occupancy). Same verified fragment mappings; m-loop deleted.
// ---------------------------------------------------------------------------
__global__ __launch_bounds__(512, 4)
void stk_main(const float* __restrict__ h,
              const int*   __restrict__ topk_idx,
              const float* __restrict__ topk_scores,
              const float* __restrict__ vb, const float* __restrict__ ob,
              const float* __restrict__ gb,
              const unsigned short* __restrict__ wsb,
              float* __restrict__ out)
{
    __shared__ __align__(16) char smem[32768];
    float (*s_P)[512] = reinterpret_cast<float(*)[512]>(smem);

    const int t   = threadIdx.x;
    // XCD swizzle: 512 blocks -> 64 consecutive tiles (= 2 batches) per XCD
    const int bid = (int)blockIdx.x;
    const int swz = ((bid & 7) << 6) + (bid >> 3);
    const int m0  = swz * ROWS;
    const int batch = m0 >> 9;

    const int lane = t & 63, w = t >> 6;
    const int n0 = 2 * w, lr = lane & 15, lg = lane >> 4;
    const int xa = (lr & 7) << 4;

    // ---- stage this block's 16 h rows to regs (bf16) -----------------------
    const int hr = t >> 5;            // 0..15 (32 thr/row)
    const int hc = (t & 31) * 8;      // 8 cols per thread
    short4v hreg[2];
    {
        const float* hrow = h + (size_t)(m0 + hr) * ND + hc;
        hreg[0] = f2bf4(*reinterpret_cast<const float4*>(hrow));
        hreg[1] = f2bf4(*reinterpret_cast<const float4*>(hrow + 4));
    }

    // ---- zero P f32 [16][512] (2048 float4 = 512 thr x 4) ------------------
    {
        float4* p4 = reinterpret_cast<float4*>(smem);
        #pragma unroll
        for (int i = 0; i < 4; ++i)
            p4[t + 512 * i] = float4{0.f, 0.f, 0.f, 0.f};
    }

    // ---- softmax over K, one (r,k) per thread ------------------------------
    const int k = t & 31;
    const int r = t >> 5;             // 0..15
    float att; int id;
    {
        const size_t off = (size_t)(m0 + r) * NK + k;
        const float s = topk_scores[off];
        id = topk_idx[off];
        float m = s;
        #pragma unroll
        for (int msk = 16; msk >= 1; msk >>= 1)
            m = fmaxf(m, __shfl_xor(m, msk));
        const float p = __expf(s - m);
        float Z = p;
        #pragma unroll
        for (int msk = 16; msk >= 1; msk >>= 1)
            Z += __shfl_xor(Z, msk);
        att = p / Z;
    }
    __syncthreads();                  // P zeroed

    atomicAdd(&s_P[r][id], att);
    __syncthreads();                  // P complete

    // ---- in-register f32->bf16 conversion of P; repartition LDS ------------
    {
        const int pr  = t >> 5;       // row 0..15 (32 thr/row)
        const int pc4 = (t & 31) * 4; // base col
        float4 pch[4];
        #pragma unroll
        for (int u = 0; u < 4; ++u)
            pch[u] = *reinterpret_cast<const float4*>(&s_P[pr][pc4 + 128 * u]);
        __syncthreads();              // all P f32 reads done

        const int xr = (pr & 7) << 4;
        #pragma unroll
        for (int u = 0; u < 4; ++u)
            *reinterpret_cast<short4v*>(
                smem + pr * 1024 + (((pc4 + 128 * u) * 2) ^ xr)) = f2bf4(pch[u]);
        const int xh = (hr & 7) << 4;
        *reinterpret_cast<short4v*>(
            smem + OFF_HB + hr * 512 + ((hc * 2) ^ xh)) = hreg[0];
        *reinterpret_cast<short4v*>(
            smem + OFF_HB + hr * 512 + (((hc + 4) * 2) ^ xh)) = hreg[1];
    }
    __syncthreads();                  // Pb + s_hb ready

    // ---- GEMM1: wsum = Pb @ h_slab -----------------------------------------
    {
        f32x4 acc[2] = {f32x4{0,0,0,0}, f32x4{0,0,0,0}};
        const unsigned short* hf = wsb + (size_t)PHB + (size_t)batch * 131072;
        #pragma unroll
        for (int ks = 0; ks < 16; ++ks) {
            short8 b[2];
            #pragma unroll
            for (int n = 0; n < 2; ++n)
                b[n] = *reinterpret_cast<const short8*>(
                    &hf[((size_t)(ks * 16 + n0 + n) * 64 + lane) * 8]);
            const int cb = (ks * 32 + lg * 8) * 2;
            const short8 a = *reinterpret_cast<const short8*>(smem + lr * 1024 + (cb ^ xa));
            #pragma unroll
            for (int n = 0; n < 2; ++n)
                acc[n] = __builtin_amdgcn_mfma_f32_16x16x32_bf16(a, b[n], acc[n], 0, 0, 0);
        }
        #pragma unroll
        for (int n = 0; n < 2; ++n) {
            const int col = (n0 + n) * 16 + lr;
            #pragma unroll
            for (int q = 0; q < 4; ++q) {
                const int row = 4 * lg + q;
                *reinterpret_cast<unsigned short*>(
                    smem + OFF_SW + row * 512 + ((col * 2) ^ ((row & 7) << 4))) =
                    f2bf(acc[n][q]);
            }
        }
    }
    __syncthreads();                  // s_w ready

    // gate accumulator: init with gb; h-half accumulated in GEMM2 phase
    f32x4 ag[2];
    #pragma unroll
    for (int n = 0; n < 2; ++n) {
        const float bg = gb[(n0 + n) * 16 + lr];
        ag[n] = f32x4{bg, bg, bg, bg};
    }

    // ---- GEMM2: agg = wsum @ vW + vb ; interleaved: ag += h @ gW_h ---------
    {
        f32x4 acc[2];
        #pragma unroll
        for (int n = 0; n < 2; ++n) {
            const float bv = vb[(n0 + n) * 16 + lr];
            acc[n] = f32x4{bv, bv, bv, bv};
        }
        #pragma unroll
        for (int ks = 0; ks < 8; ++ks) {
            short8 b_v[2], b_g1[2];
            #pragma unroll
            for (int n = 0; n < 2; ++n) {
                const int nt = n0 + n;
                b_v[n]  = *reinterpret_cast<const short8*>(
                    &wsb[(size_t)(PVW + ((nt * 8 + ks) * 64 + lane) * 8)]);
                b_g1[n] = *reinterpret_cast<const short8*>(
                    &wsb[(size_t)(PGW + ((nt * 16 + ks) * 64 + lane) * 8)]);
            }
            const int cb = (ks * 32 + lg * 8) * 2;
            const short8 a  = *reinterpret_cast<const short8*>(smem + OFF_SW + lr * 512 + (cb ^ xa));
            const short8 ah = *reinterpret_cast<const short8*>(smem + OFF_HB + lr * 512 + (cb ^ xa));
            #pragma unroll
            for (int n = 0; n < 2; ++n) {
                acc[n] = __builtin_amdgcn_mfma_f32_16x16x32_bf16(a,  b_v[n],  acc[n], 0, 0, 0);
                ag[n]  = __builtin_amdgcn_mfma_f32_16x16x32_bf16(ah, b_g1[n], ag[n],  0, 0, 0);
            }
        }
        // s_ab over dead Pb region [0,8192); no reader until next barrier
        #pragma unroll
        for (int n = 0; n < 2; ++n) {
            const int col = (n0 + n) * 16 + lr;
            #pragma unroll
            for (int q = 0; q < 4; ++q) {
                const int row = 4 * lg + q;
                *reinterpret_cast<unsigned short*>(
                    smem + row * 512 + ((col * 2) ^ ((row & 7) << 4))) =
                    f2bf(acc[n][q]);
            }
        }
    }
    __syncthreads();                  // s_ab ready

    // ---- GEMM3: o = agg@oW + ob ; ag += agg@gW_a ; epilogue ----------------
    {
        f32x4 ao[2];
        #pragma unroll
        for (int n = 0; n < 2; ++n) {
            const float bo = ob[(n0 + n) * 16 + lr];
            ao[n] = f32x4{bo, bo, bo, bo};
        }
        #pragma unroll
        for (int ks = 0; ks < 8; ++ks) {
            short8 b_o[2], b_g2[2];
            #pragma unroll
            for (int n = 0; n < 2; ++n) {
                const int nt = n0 + n;
                b_o[n]  = *reinterpret_cast<const short8*>(
                    &wsb[(size_t)(POW + ((nt * 8 + ks) * 64 + lane) * 8)]);
                b_g2[n] = *reinterpret_cast<const short8*>(
                    &wsb[(size_t)(PGW + ((nt * 16 + ks + 8) * 64 + lane) * 8)]);
            }
            const int cb = (ks * 32 + lg * 8) * 2;
            const short8 aa = *reinterpret_cast<const short8*>(smem + lr * 512 + (cb ^ xa));
            #pragma unroll
            for (int n = 0; n < 2; ++n) {
                ao[n] = __builtin_amdgcn_mfma_f32_16x16x32_bf16(aa, b_o[n],  ao[n], 0, 0, 0);
                ag[n] = __builtin_amdgcn_mfma_f32_16x16x32_bf16(aa, b_g2[n], ag[n], 0, 0, 0);
            }
        }
        #pragma unroll
        for (int n = 0; n < 2; ++n) {
            const int col = (n0 + n) * 16 + lr;
            #pragma unroll
            for (int q = 0; q < 4; ++q) {
                const int row = m0 + 4 * lg + q;
                const float g = 1.f / (1.f + __expf(-ag[n][q]));
                out[(size_t)row * ND + col] = g * ao[n][q];
            }
        }
    }
}

// ---------------------------------------------------------------------------
// fallback: proven f32 kernel (used only if ws_size < WS_NEED)
// ---------------------------------------------------------------------------
__global__ __launch_bounds__(512, 2)
void stk_fused(const float* __restrict__ h,
               const int*   __restrict__ topk_idx,
               const float* __restrict__ topk_scores,
               const float* __restrict__ vW, const float* __restrict__ vb,
               const float* __restrict__ oW, const float* __restrict__ ob,
               const float* __restrict__ gW, const float* __restrict__ gb,
               float* __restrict__ out)
{
    __shared__ float s_attn[32][NK];
    __shared__ int   s_idx [32][NK];
    __shared__ float s_wsum[32][ND];
    __shared__ float s_h   [32][ND];
    __shared__ float s_agg [32][ND];

    const int t  = threadIdx.x;
    const int m0 = blockIdx.x * 32;
    const size_t hb = (size_t)(m0 >> 9) * NC * ND;

    {
        const int k  = t & 31;
        const int r0 = t >> 5;
        #pragma unroll
        for (int half = 0; half < 2; ++half) {
            const int r = r0 + (half << 4);
            const size_t off = (size_t)(m0 + r) * NK + k;
            const float s = topk_scores[off];
            const int  id = topk_idx[off];
            float m = s;
            #pragma unroll
            for (int msk = 16; msk >= 1; msk >>= 1) m = fmaxf(m, __shfl_xor(m, msk));
            const float p = __expf(s - m);
            float Z = p;
            #pragma unroll
            for (int msk = 16; msk >= 1; msk >>= 1) Z += __shfl_xor(Z, msk);
            s_attn[r][k] = p / Z;
            s_idx [r][k] = id;
        }
    }
    __syncthreads();

    const int d  = t & 127;
    const int rb = (t >> 7) * 8;

    #pragma unroll
    for (int i = 0; i < 8; ++i) {
        const int r = rb + i;
        const size_t ro = (size_t)(m0 + r) * ND;
        s_h[r][d]       = h[ro + d];
        s_h[r][d + 128] = h[ro + d + 128];
    }
    #pragma unroll 1
    for (int i = 0; i < 8; ++i) {
        const int r = rb + i;
        float a0 = 0.f, a1 = 0.f;
        #pragma unroll 8
        for (int k = 0; k < NK; ++k) {
            const float w  = s_attn[r][k];
            const size_t nb = hb + (size_t)s_idx[r][k] * ND;
            a0 = fmaf(w, h[nb + d],       a0);
            a1 = fmaf(w, h[nb + d + 128], a1);
        }
        s_wsum[r][d]       = a0;
        s_wsum[r][d + 128] = a1;
    }
    __syncthreads();

    float agg0[8], agg1[8];
    {
        const float b0 = vb[d], b1 = vb[d + 128];
        #pragma unroll
        for (int i = 0; i < 8; ++i) { agg0[i] = b0; agg1[i] = b1; }
        for (int e0 = 0; e0 < ND; e0 += 4) {
            float w0[4], w1[4];
            #pragma unroll
            for (int j = 0; j < 4; ++j) {
                w0[j] = vW[(size_t)(e0 + j) * ND + d];
                w1[j] = vW[(size_t)(e0 + j) * ND + d + 128];
            }
            #pragma unroll
            for (int i = 0; i < 8; ++i) {
                const float4 a = *reinterpret_cast<const float4*>(&s_wsum[rb + i][e0]);
                agg0[i] = fmaf(a.x, w0[0], agg0[i]); agg1[i] = fmaf(a.x, w1[0], agg1[i]);
                agg0[i] = fmaf(a.y, w0[1], agg0[i]); agg1[i] = fmaf(a.y, w1[1], agg1[i]);
                agg0[i] = fmaf(a.z, w0[2], agg0[i]); agg1[i] = fmaf(a.z, w1[2], agg1[i]);
                agg0[i] = fmaf(a.w, w0[3], agg0[i]); agg1[i] = fmaf(a.w, w1[3], agg1[i]);
            }
        }
        #pragma unroll
        for (int i = 0; i < 8; ++i) {
            s_agg[rb + i][d]       = agg0[i];
            s_agg[rb + i][d + 128] = agg1[i];
        }
    }
    __syncthreads();

    float o0[8], o1[8], g0[8], g1[8];
    {
        const float obb0 = ob[d], obb1 = ob[d + 128];
        const float gbb0 = gb[d], gbb1 = gb[d + 128];
        #pragma unroll
        for (int i = 0; i < 8; ++i) { o0[i]=obb0; o1[i]=obb1; g0[i]=gbb0; g1[i]=gbb1; }
        for (int e0 = 0; e0 < ND; e0 += 4) {
            float ow0[4], ow1[4], gh0[4], gh1[4], ga0[4], ga1[4];
            #pragma unroll
            for (int j = 0; j < 4; ++j) {
                const size_t er = (size_t)(e0 + j) * ND;
                ow0[j] = oW[er + d];                    ow1[j] = oW[er + d + 128];
                gh0[j] = gW[er + d];                    gh1[j] = gW[er + d + 128];
                ga0[j] = gW[er + (size_t)ND * ND + d];  ga1[j] = gW[er + (size_t)ND * ND + d + 128];
            }
            #pragma unroll
            for (int i = 0; i < 8; ++i) {
                const float4 a  = *reinterpret_cast<const float4*>(&s_agg[rb + i][e0]);
                const float4 hh = *reinterpret_cast<const float4*>(&s_h  [rb + i][e0]);
                o0[i] = fmaf(a.x, ow0[0], o0[i]); o0[i] = fmaf(a.y, ow0[1], o0[i]);
                o0[i] = fmaf(a.z, ow0[2], o0[i]); o0[i] = fmaf(a.w, ow0[3], o0[i]);
                o1[i] = fmaf(a.x, ow1[0], o1[i]); o1[i] = fmaf(a.y, ow1[1], o1[i]);
                o1[i] = fmaf(a.z, ow1[2], o1[i]); o1[i] = fmaf(a.w, ow1[3], o1[i]);
                g0[i] = fmaf(hh.x, gh0[0], g0[i]); g0[i] = fmaf(hh.y, gh0[1], g0[i]);
                g0[i] = fmaf(hh.z, gh0[2], g0[i]); g0[i] = fmaf(hh.w, gh0[3], g0[i]);
                g1[i] = fmaf(hh.x, gh1[0], g1[i]); g1[i] = fmaf(hh.y, gh1[1], g1[i]);
                g1[i] = fmaf(hh.z, gh1[2], g1[i]); g1[i] = fmaf(hh.w, gh1[3], g1[i]);
                g0[i] = fmaf(a.x, ga0[0], g0[i]); g0[i] = fmaf(a.y, ga0[1], g0[i]);
                g0[i] = fmaf(a.z, ga0[2], g0[i]); g0[i] = fmaf(a.w, ga0[3], g0[i]);
                g1[i] = fmaf(a.x, ga1[0], g1[i]); g1[i] = fmaf(a.y, ga1[1], g1[i]);
                g1[i] = fmaf(a.z, ga1[2], g1[i]); g1[i] = fmaf(a.w, ga1[3], g1[i]);
            }
        }
    }
    #pragma unroll
    for (int i = 0; i < 8; ++i) {
        const size_t ro = (size_t)(m0 + rb + i) * ND;
        const float sg0 = 1.f / (1.f + __expf(-g0[i]));
        const float sg1 = 1.f / (1.f + __expf(-g1[i]));
        out[ro + d]       = sg0 * o0[i];
        out[ro + d + 128] = sg1 * o1[i];
    }
}

extern "C" void kernel_launch(void* const* d_in, const int* in_sizes, int n_in,
                              void* d_out, int out_size, void* d_ws, size_t ws_size,
                              hipStream_t stream) {
    const float* h   = (const float*)d_in[0];
    const int*   idx = (const int*)  d_in[1];
    const float* sc  = (const float*)d_in[2];
    const float* vW  = (const float*)d_in[3];
    const float* vb  = (const float*)d_in[4];
    const float* oW  = (const float*)d_in[5];
    const float* ob  = (const float*)d_in[6];
    const float* gW  = (const float*)d_in[7];
    const float* gb  = (const float*)d_in[8];
    float* out = (float*)d_out;

    if (ws_size >= WS_NEED) {
        unsigned short* wsb = (unsigned short*)d_ws;
        stk_pack_all<<<1152, 256, 0, stream>>>(vW, oW, gW, h, wsb);
        stk_main    <<<NBLK, NTHR, 0, stream>>>(h, idx, sc, vb, ob, gb, wsb, out);
    } else {
        stk_fused<<<256, 512, 0, stream>>>(h, idx, sc, vW, vb, oW, ob, gW, gb, out);
    }
}

// Round 15
// 25.609 us; speedup vs baseline: 1.1421x; 1.1421x over previous
//
#include <hip/hip_runtime.h>
#include <hip/hip_bf16.h>
#include <cstdint>
#include <cstddef>

using short8  = __attribute__((ext_vector_type(8))) short;
using short4v = __attribute__((ext_vector_type(4))) short;
using f32x4   = __attribute__((ext_vector_type(4))) float;

constexpr int NB = 16, NC = 512, ND = 256, NK = 32;
constexpr int ROWS = 32;               // rows per block
constexpr int NROW = NB * NC;          // 8192
constexpr int NBLK = NROW / ROWS;      // 256
constexpr int NTHR = 512;              // 8 waves

// single 64 KB LDS region, repartitioned over time (R9-verified):
//  phase 1: P f32 [32][512]
//  phase 2: Pb bf16 [32][512] swz @0 ; s_w @32768 ; s_hb @49152
//  phase 3: s_ab bf16 [32][256] swz @0 (over dead Pb)
constexpr int OFF_SW = 32768;
constexpr int OFF_HB = 49152;

// d_ws layout (bf16 element offsets) — R6/R9-verified:
//  vW frags [0,65536): fl=nt*8+ks ; oW [65536,131072) ; gW [131072,262144): fl=nt*16+ks
//  h  frags [262144 + b*131072): frag fs=ks*16+nt
constexpr int PVW = 0;
constexpr int POW = 65536;
constexpr int PGW = 131072;
constexpr int PHB = 262144;
constexpr size_t WS_NEED = (size_t)(PHB + NB * 131072) * 2;   // ~4.7 MB

static __device__ __forceinline__ unsigned short f2bf(float f) {
    __hip_bfloat16 b = __float2bfloat16(f);
    return *reinterpret_cast<unsigned short*>(&b);
}
static __device__ __forceinline__ short4v f2bf4(float4 v) {
    short4v r;
    r[0] = (short)f2bf(v.x); r[1] = (short)f2bf(v.y);
    r[2] = (short)f2bf(v.z); r[3] = (short)f2bf(v.w);
    return r;
}

// ---------------------------------------------------------------------------
// pack: blocks 0..127 pack weights with NON-TEMPORAL stores (bypass producer
// L2 -> clean lines in shared L3, read by all 8 XCDs); blocks 128..1151 pack
// h-slabs XCD-CO-LOCATED with their consumers: main block swizzle puts
// batches {2x,2x+1} on XCD x; h-pack block at grid pos g sits on XCD g%8,
// so we assign batch b to pack blocks with (128+j)%8 == b/2.
// ---------------------------------------------------------------------------
__global__ __launch_bounds__(256)
void stk_pack_all(const float* __restrict__ vW, const float* __restrict__ oW,
                  const float* __restrict__ gW, const float* __restrict__ h,
                  unsigned short* __restrict__ ws)
{
    const int blk = blockIdx.x;
    if (blk < 128) {
        const int tid  = blk * 256 + threadIdx.x;      // 32768 threads
        const int lane = tid & 63;
        const int fl   = tid >> 6;                     // 0..511
        const float* src; int nt, ks;
        if (fl < 128)      { src = vW; nt = fl >> 3;         ks = fl & 7;          }
        else if (fl < 256) { src = oW; nt = (fl - 128) >> 3; ks = (fl - 128) & 7;  }
        else               { src = gW; nt = (fl - 256) >> 4; ks = (fl - 256) & 15; }
        const int col = nt * 16 + (lane & 15);
        const int k0  = ks * 32 + (lane >> 4) * 8;
        short8 v;
        #pragma unroll
        for (int j = 0; j < 8; ++j)
            v[j] = (short)f2bf(src[(size_t)(k0 + j) * ND + col]);
        __builtin_nontemporal_store(v, reinterpret_cast<short8*>(&ws[(size_t)tid * 8]));
    } else {
        const int j   = blk - 128;                     // 0..1023
        const int x   = j & 7;                         // target XCD (= grid%8)
        const int s   = j >> 3;                        // 0..127
        const int b   = 2 * x + (s >> 6);              // batch consumed on XCD x
        const int wbi = s & 63;                        // 0..63: block within batch
        const int tfr = threadIdx.x >> 6;              // 0..3: frag within block
        const int lane = threadIdx.x & 63;
        const int fs  = b * 256 + wbi * 4 + tfr;       // b*256 + ks*16 + nt
        const int ks  = (fs >> 4) & 15;
        const int nt  = fs & 15;
        const float* src = h + (size_t)b * NC * ND;
        const int col = nt * 16 + (lane & 15);
        const int k0  = ks * 32 + (lane >> 4) * 8;
        short8 v;
        #pragma unroll
        for (int jj = 0; jj < 8; ++jj)
            v[jj] = (short)f2bf(src[(size_t)(k0 + jj) * ND + col]);
        *reinterpret_cast<short8*>(&ws[(size_t)PHB + (size_t)fs * 512 + (size_t)lane * 8]) = v;
    }
}

// ---------------------------------------------------------------------------
// main fused kernel (R13 body, 29.1 us band): 32 rows/block, 512 threads,
// 64 KB LDS -> 2 blocks/CU.
// ---------------------------------------------------------------------------
__global__ __launch_bounds__(512, 2)
void stk_main(const float* __restrict__ h,
              const int*   __restrict__ topk_idx,
              const float* __restrict__ topk_scores,
              const float* __restrict__ vb, const float* __restrict__ ob,
              const float* __restrict__ gb,
              const unsigned short* __restrict__ wsb,
              float* __restrict__ out)
{
    __shared__ __align__(16) char smem[65536];
    float (*s_P)[512] = reinterpret_cast<float(*)[512]>(smem);

    const int t   = threadIdx.x;
    // XCD swizzle: 256 blocks -> 32 consecutive tiles (2 batches) per XCD
    const int bid = (int)blockIdx.x;
    const int swz = ((bid & 7) << 5) + (bid >> 3);
    const int m0  = swz * ROWS;
    const int batch = m0 >> 9;

    const int lane = t & 63, w = t >> 6;
    const int n0 = 2 * w, lr = lane & 15, lg = lane >> 4;
    const int xa = (lr & 7) << 4;     // row-XOR for rows lr and lr+16 (same &7)

    // ---- stage this block's 32 h rows to regs (bf16), consumed later -------
    const int hr = t >> 4;            // 0..31
    const int hc = (t & 15) * 16;     // 16 cols per thread
    short4v hreg[4];
    {
        const float* hrow = h + (size_t)(m0 + hr) * ND + hc;
        #pragma unroll
        for (int u = 0; u < 4; ++u)
            hreg[u] = f2bf4(*reinterpret_cast<const float4*>(hrow + 4 * u));
    }

    // ---- zero P f32 [32][512] (4096 float4 = 512 thr x 8) ------------------
    {
        float4* p4 = reinterpret_cast<float4*>(smem);
        #pragma unroll
        for (int i = 0; i < 8; ++i)
            p4[t + 512 * i] = float4{0.f, 0.f, 0.f, 0.f};
    }

    // ---- softmax over K, two rows per thread -------------------------------
    const int k  = t & 31;
    const int r0 = t >> 5;            // 0..15
    float att[2]; int id[2];
    #pragma unroll
    for (int half = 0; half < 2; ++half) {
        const int r = r0 + (half << 4);
        const size_t off = (size_t)(m0 + r) * NK + k;
        const float s = topk_scores[off];
        id[half] = topk_idx[off];
        float m = s;
        #pragma unroll
        for (int msk = 16; msk >= 1; msk >>= 1)
            m = fmaxf(m, __shfl_xor(m, msk));
        const float p = __expf(s - m);
        float Z = p;
        #pragma unroll
        for (int msk = 16; msk >= 1; msk >>= 1)
            Z += __shfl_xor(Z, msk);
        att[half] = p / Z;
    }
    __syncthreads();                  // P zeroed

    atomicAdd(&s_P[r0][id[0]],      att[0]);
    atomicAdd(&s_P[r0 + 16][id[1]], att[1]);
    __syncthreads();                  // P complete

    // ---- in-register f32->bf16 conversion of P; repartition LDS ------------
    {
        const int pr  = t >> 4;       // row 0..31 (16 thr/row)
        const int pc4 = (t & 15) * 4; // base col
        float4 pch[8];
        #pragma unroll
        for (int u = 0; u < 8; ++u)
            pch[u] = *reinterpret_cast<const float4*>(&s_P[pr][pc4 + 64 * u]);
        __syncthreads();              // all P f32 reads done

        const int xr = (pr & 7) << 4;
        #pragma unroll
        for (int u = 0; u < 8; ++u)
            *reinterpret_cast<short4v*>(
                smem + pr * 1024 + (((pc4 + 64 * u) * 2) ^ xr)) = f2bf4(pch[u]);
        const int xh = (hr & 7) << 4;
        #pragma unroll
        for (int u = 0; u < 4; ++u)
            *reinterpret_cast<short4v*>(
                smem + OFF_HB + hr * 512 + (((hc + 4 * u) * 2) ^ xh)) = hreg[u];
    }
    __syncthreads();                  // Pb + s_hb ready

    // ---- GEMM1: wsum = Pb @ h_slab ------------------------------------------
    {
        f32x4 acc[2][2] = {{f32x4{0,0,0,0}, f32x4{0,0,0,0}},
                           {f32x4{0,0,0,0}, f32x4{0,0,0,0}}};
        const unsigned short* hf = wsb + (size_t)PHB + (size_t)batch * 131072;
        #pragma unroll
        for (int ks = 0; ks < 16; ++ks) {
            short8 b[2];
            #pragma unroll
            for (int n = 0; n < 2; ++n)
                b[n] = *reinterpret_cast<const short8*>(
                    &hf[((size_t)(ks * 16 + n0 + n) * 64 + lane) * 8]);
            const int cb = (ks * 32 + lg * 8) * 2;
            short8 a[2];
            a[0] = *reinterpret_cast<const short8*>(smem + lr * 1024 + (cb ^ xa));
            a[1] = *reinterpret_cast<const short8*>(smem + (16 + lr) * 1024 + (cb ^ xa));
            #pragma unroll
            for (int n = 0; n < 2; ++n) {
                acc[0][n] = __builtin_amdgcn_mfma_f32_16x16x32_bf16(a[0], b[n], acc[0][n], 0, 0, 0);
                acc[1][n] = __builtin_amdgcn_mfma_f32_16x16x32_bf16(a[1], b[n], acc[1][n], 0, 0, 0);
            }
        }
        #pragma unroll
        for (int m = 0; m < 2; ++m)
            #pragma unroll
            for (int n = 0; n < 2; ++n) {
                const int col = (n0 + n) * 16 + lr;
                #pragma unroll
                for (int q = 0; q < 4; ++q) {
                    const int row = m * 16 + 4 * lg + q;
                    *reinterpret_cast<unsigned short*>(
                        smem + OFF_SW + row * 512 + ((col * 2) ^ ((row & 7) << 4))) =
                        f2bf(acc[m][n][q]);
                }
            }
    }
    __syncthreads();                  // s_w ready

    // gate accumulator: init with gb; h-half accumulated in GEMM2 phase
    f32x4 ag[2][2];
    #pragma unroll
    for (int n = 0; n < 2; ++n) {
        const float bg = gb[(n0 + n) * 16 + lr];
        ag[0][n] = f32x4{bg, bg, bg, bg};
        ag[1][n] = ag[0][n];
    }

    // ---- GEMM2: agg = wsum @ vW + vb ; interleaved: ag += h @ gW_h ---------
    {
        f32x4 acc[2][2];
        #pragma unroll
        for (int n = 0; n < 2; ++n) {
            const float bv = vb[(n0 + n) * 16 + lr];
            acc[0][n] = f32x4{bv, bv, bv, bv};
            acc[1][n] = f32x4{bv, bv, bv, bv};
        }
        #pragma unroll
        for (int ks = 0; ks < 8; ++ks) {
            short8 b_v[2], b_g1[2];
            #pragma unroll
            for (int n = 0; n < 2; ++n) {
                const int nt = n0 + n;
                b_v[n]  = *reinterpret_cast<const short8*>(
                    &wsb[(size_t)(PVW + ((nt * 8 + ks) * 64 + lane) * 8)]);
                b_g1[n] = *reinterpret_cast<const short8*>(
                    &wsb[(size_t)(PGW + ((nt * 16 + ks) * 64 + lane) * 8)]);
            }
            const int cb = (ks * 32 + lg * 8) * 2;
            short8 a[2], ah[2];
            a[0]  = *reinterpret_cast<const short8*>(smem + OFF_SW + lr * 512 + (cb ^ xa));
            a[1]  = *reinterpret_cast<const short8*>(smem + OFF_SW + (16 + lr) * 512 + (cb ^ xa));
            ah[0] = *reinterpret_cast<const short8*>(smem + OFF_HB + lr * 512 + (cb ^ xa));
            ah[1] = *reinterpret_cast<const short8*>(smem + OFF_HB + (16 + lr) * 512 + (cb ^ xa));
            #pragma unroll
            for (int n = 0; n < 2; ++n) {
                acc[0][n] = __builtin_amdgcn_mfma_f32_16x16x32_bf16(a[0],  b_v[n],  acc[0][n], 0, 0, 0);
                acc[1][n] = __builtin_amdgcn_mfma_f32_16x16x32_bf16(a[1],  b_v[n],  acc[1][n], 0, 0, 0);
                ag[0][n]  = __builtin_amdgcn_mfma_f32_16x16x32_bf16(ah[0], b_g1[n], ag[0][n],  0, 0, 0);
                ag[1][n]  = __builtin_amdgcn_mfma_f32_16x16x32_bf16(ah[1], b_g1[n], ag[1][n],  0, 0, 0);
            }
        }
        // s_ab over dead Pb region [0,16384); no reader until next barrier
        #pragma unroll
        for (int m = 0; m < 2; ++m)
            #pragma unroll
            for (int n = 0; n < 2; ++n) {
                const int col = (n0 + n) * 16 + lr;
                #pragma unroll
                for (int q = 0; q < 4; ++q) {
                    const int row = m * 16 + 4 * lg + q;
                    *reinterpret_cast<unsigned short*>(
                        smem + row * 512 + ((col * 2) ^ ((row & 7) << 4))) =
                        f2bf(acc[m][n][q]);
                }
            }
    }
    __syncthreads();                  // s_ab ready

    // ---- GEMM3: o = agg@oW + ob ; ag += agg@gW_a ; epilogue ----------------
    {
        f32x4 ao[2][2];
        #pragma unroll
        for (int n = 0; n < 2; ++n) {
            const float bo = ob[(n0 + n) * 16 + lr];
            ao[0][n] = f32x4{bo, bo, bo, bo};
            ao[1][n] = ao[0][n];
        }
        #pragma unroll
        for (int ks = 0; ks < 8; ++ks) {
            short8 b_o[2], b_g2[2];
            #pragma unroll
            for (int n = 0; n < 2; ++n) {
                const int nt = n0 + n;
                b_o[n]  = *reinterpret_cast<const short8*>(
                    &wsb[(size_t)(POW + ((nt * 8 + ks) * 64 + lane) * 8)]);
                b_g2[n] = *reinterpret_cast<const short8*>(
                    &wsb[(size_t)(PGW + ((nt * 16 + ks + 8) * 64 + lane) * 8)]);
            }
            const int cb = (ks * 32 + lg * 8) * 2;
            short8 aa[2];
            aa[0] = *reinterpret_cast<const short8*>(smem + lr * 512 + (cb ^ xa));
            aa[1] = *reinterpret_cast<const short8*>(smem + (16 + lr) * 512 + (cb ^ xa));
            #pragma unroll
            for (int n = 0; n < 2; ++n) {
                #pragma unroll
                for (int m = 0; m < 2; ++m) {
                    ao[m][n] = __builtin_amdgcn_mfma_f32_16x16x32_bf16(aa[m], b_o[n],  ao[m][n], 0, 0, 0);
                    ag[m][n] = __builtin_amdgcn_mfma_f32_16x16x32_bf16(aa[m], b_g2[n], ag[m][n], 0, 0, 0);
                }
            }
        }
        #pragma unroll
        for (int m = 0; m < 2; ++m)
            #pragma unroll
            for (int n = 0; n < 2; ++n) {
                const int col = (n0 + n) * 16 + lr;
                #pragma unroll
                for (int q = 0; q < 4; ++q) {
                    const int row = m0 + m * 16 + 4 * lg + q;
                    const float g = 1.f / (1.f + __expf(-ag[m][n][q]));
                    out[(size_t)row * ND + col] = g * ao[m][n][q];
                }
            }
    }
}

// ---------------------------------------------------------------------------
// fallback: proven f32 kernel (used only if ws_size < WS_NEED)
// ---------------------------------------------------------------------------
__global__ __launch_bounds__(512, 2)
void stk_fused(const float* __restrict__ h,
               const int*   __restrict__ topk_idx,
               const float* __restrict__ topk_scores,
               const float* __restrict__ vW, const float* __restrict__ vb,
               const float* __restrict__ oW, const float* __restrict__ ob,
               const float* __restrict__ gW, const float* __restrict__ gb,
               float* __restrict__ out)
{
    __shared__ float s_attn[32][NK];
    __shared__ int   s_idx [32][NK];
    __shared__ float s_wsum[32][ND];
    __shared__ float s_h   [32][ND];
    __shared__ float s_agg [32][ND];

    const int t  = threadIdx.x;
    const int m0 = blockIdx.x * 32;
    const size_t hb = (size_t)(m0 >> 9) * NC * ND;

    {
        const int k  = t & 31;
        const int r0 = t >> 5;
        #pragma unroll
        for (int half = 0; half < 2; ++half) {
            const int r = r0 + (half << 4);
            const size_t off = (size_t)(m0 + r) * NK + k;
            const float s = topk_scores[off];
            const int  id = topk_idx[off];
            float m = s;
            #pragma unroll
            for (int msk = 16; msk >= 1; msk >>= 1) m = fmaxf(m, __shfl_xor(m, msk));
            const float p = __expf(s - m);
            float Z = p;
            #pragma unroll
            for (int msk = 16; msk >= 1; msk >>= 1) Z += __shfl_xor(Z, msk);
            s_attn[r][k] = p / Z;
            s_idx [r][k] = id;
        }
    }
    __syncthreads();

    const int d  = t & 127;
    const int rb = (t >> 7) * 8;

    #pragma unroll
    for (int i = 0; i < 8; ++i) {
        const int r = rb + i;
        const size_t ro = (size_t)(m0 + r) * ND;
        s_h[r][d]       = h[ro + d];
        s_h[r][d + 128] = h[ro + d + 128];
    }
    #pragma unroll 1
    for (int i = 0; i < 8; ++i) {
        const int r = rb + i;
        float a0 = 0.f, a1 = 0.f;
        #pragma unroll 8
        for (int k = 0; k < NK; ++k) {
            const float w  = s_attn[r][k];
            const size_t nb = hb + (size_t)s_idx[r][k] * ND;
            a0 = fmaf(w, h[nb + d],       a0);
            a1 = fmaf(w, h[nb + d + 128], a1);
        }
        s_wsum[r][d]       = a0;
        s_wsum[r][d + 128] = a1;
    }
    __syncthreads();

    float agg0[8], agg1[8];
    {
        const float b0 = vb[d], b1 = vb[d + 128];
        #pragma unroll
        for (int i = 0; i < 8; ++i) { agg0[i] = b0; agg1[i] = b1; }
        for (int e0 = 0; e0 < ND; e0 += 4) {
            float w0[4], w1[4];
            #pragma unroll
            for (int j = 0; j < 4; ++j) {
                w0[j] = vW[(size_t)(e0 + j) * ND + d];
                w1[j] = vW[(size_t)(e0 + j) * ND + d + 128];
            }
            #pragma unroll
            for (int i = 0; i < 8; ++i) {
                const float4 a = *reinterpret_cast<const float4*>(&s_wsum[rb + i][e0]);
                agg0[i] = fmaf(a.x, w0[0], agg0[i]); agg1[i] = fmaf(a.x, w1[0], agg1[i]);
                agg0[i] = fmaf(a.y, w0[1], agg0[i]); agg1[i] = fmaf(a.y, w1[1], agg1[i]);
                agg0[i] = fmaf(a.z, w0[2], agg0[i]); agg1[i] = fmaf(a.z, w1[2], agg1[i]);
                agg0[i] = fmaf(a.w, w0[3], agg0[i]); agg1[i] = fmaf(a.w, w1[3], agg1[i]);
            }
        }
        #pragma unroll
        for (int i = 0; i < 8; ++i) {
            s_agg[rb + i][d]       = agg0[i];
            s_agg[rb + i][d + 128] = agg1[i];
        }
    }
    __syncthreads();

    float o0[8], o1[8], g0[8], g1[8];
    {
        const float obb0 = ob[d], obb1 = ob[d + 128];
        const float gbb0 = gb[d], gbb1 = gb[d + 128];
        #pragma unroll
        for (int i = 0; i < 8; ++i) { o0[i]=obb0; o1[i]=obb1; g0[i]=gbb0; g1[i]=gbb1; }
        for (int e0 = 0; e0 < ND; e0 += 4) {
            float ow0[4], ow1[4], gh0[4], gh1[4], ga0[4], ga1[4];
            #pragma unroll
            for (int j = 0; j < 4; ++j) {
                const size_t er = (size_t)(e0 + j) * ND;
                ow0[j] = oW[er + d];                    ow1[j] = oW[er + d + 128];
                gh0[j] = gW[er + d];                    gh1[j] = gW[er + d + 128];
                ga0[j] = gW[er + (size_t)ND * ND + d];  ga1[j] = gW[er + (size_t)ND * ND + d + 128];
            }
            #pragma unroll
            for (int i = 0; i < 8; ++i) {
                const float4 a  = *reinterpret_cast<const float4*>(&s_agg[rb + i][e0]);
                const float4 hh = *reinterpret_cast<const float4*>(&s_h  [rb + i][e0]);
                o0[i] = fmaf(a.x, ow0[0], o0[i]); o0[i] = fmaf(a.y, ow0[1], o0[i]);
                o0[i] = fmaf(a.z, ow0[2], o0[i]); o0[i] = fmaf(a.w, ow0[3], o0[i]);
                o1[i] = fmaf(a.x, ow1[0], o1[i]); o1[i] = fmaf(a.y, ow1[1], o1[i]);
                o1[i] = fmaf(a.z, ow1[2], o1[i]); o1[i] = fmaf(a.w, ow1[3], o1[i]);
                g0[i] = fmaf(hh.x, gh0[0], g0[i]); g0[i] = fmaf(hh.y, gh0[1], g0[i]);
                g0[i] = fmaf(hh.z, gh0[2], g0[i]); g0[i] = fmaf(hh.w, gh0[3], g0[i]);
                g1[i] = fmaf(hh.x, gh1[0], g1[i]); g1[i] = fmaf(hh.y, gh1[1], g1[i]);
                g1[i] = fmaf(hh.z, gh1[2], g1[i]); g1[i] = fmaf(hh.w, gh1[3], g1[i]);
                g0[i] = fmaf(a.x, ga0[0], g0[i]); g0[i] = fmaf(a.y, ga0[1], g0[i]);
                g0[i] = fmaf(a.z, ga0[2], g0[i]); g0[i] = fmaf(a.w, ga0[3], g0[i]);
                g1[i] = fmaf(a.x, ga1[0], g1[i]); g1[i] = fmaf(a.y, ga1[1], g1[i]);
                g1[i] = fmaf(a.z, ga1[2], g1[i]); g1[i] = fmaf(a.w, ga1[3], g1[i]);
            }
        }
    }
    #pragma unroll
    for (int i = 0; i < 8; ++i) {
        const size_t ro = (size_t)(m0 + rb + i) * ND;
        const float sg0 = 1.f / (1.f + __expf(-g0[i]));
        const float sg1 = 1.f / (1.f + __expf(-g1[i]));
        out[ro + d]       = sg0 * o0[i];
        out[ro + d + 128] = sg1 * o1[i];
    }
}

extern "C" void kernel_launch(void* const* d_in, const int* in_sizes, int n_in,
                              void* d_out, int out_size, void* d_ws, size_t ws_size,
                              hipStream_t stream) {
    const float* h   = (const float*)d_in[0];
    const int*   idx = (const int*)  d_in[1];
    const float* sc  = (const float*)d_in[2];
    const float* vW  = (const float*)d_in[3];
    const float* vb  = (const float*)d_in[4];
    const float* oW  = (const float*)d_in[5];
    const float* ob  = (const float*)d_in[6];
    const float* gW  = (const float*)d_in[7];
    const float* gb  = (const float*)d_in[8];
    float* out = (float*)d_out;

    if (ws_size >= WS_NEED) {
        unsigned short* wsb = (unsigned short*)d_ws;
        stk_pack_all<<<1152, 256, 0, stream>>>(vW, oW, gW, h, wsb);
        stk_main    <<<NBLK, NTHR, 0, stream>>>(h, idx, sc, vb, ob, gb, wsb, out);
    } else {
        stk_fused<<<256, 512, 0, stream>>>(h, idx, sc, vW, vb, oW, ob, gW, gb, out);
    }
}